// Round 17
// baseline (101.468 us; speedup 1.0000x reference)
//
#include <hip/hip_runtime.h>
#include <hip/hip_bf16.h>

#define B_    8
#define S_    32
#define H_    2048
#define NH_   16
#define NKV_  2
#define HD_   128
#define KV_   8192
#define G_    8
#define M_    256      /* B*S */
#define NQKV  2560     /* fused proj N: 2048 q | 256 k | 256 v */
#define NSP   16       /* kv splits */
#define KT_   64       /* kv subtile */
#define NT_   8        /* subtiles per block = KV_/NSP/KT_ */
#define SCALE_ 0.08838834764831845f
#define CFIX_  8.0f
#define LOG2E_ 1.4426950408889634f
#define SCALE2_ (SCALE_*LOG2E_)

typedef __bf16 bf16x8 __attribute__((ext_vector_type(8)));
typedef float  f32x4  __attribute__((ext_vector_type(4)));
typedef float  f32x16 __attribute__((ext_vector_type(16)));

__device__ __forceinline__ unsigned short f2b(float f){
  unsigned u = __float_as_uint(f);
  u = u + 0x7FFFu + ((u>>16)&1u);           // RNE f32->bf16
  return (unsigned short)(u>>16);
}
__device__ __forceinline__ float b2f(unsigned short h){
  return __uint_as_float(((unsigned)h)<<16);
}
// HW packed f32->bf16 pair (T12 recipe; no builtin on gfx950)
__device__ __forceinline__ unsigned cvtpk(float lo, float hi){
  unsigned r;
  asm("v_cvt_pk_bf16_f32 %0, %1, %2" : "=v"(r) : "v"(lo), "v"(hi));
  return r;
}
// raw v_exp_f32 (2^x)
__device__ __forceinline__ float fexp2(float x){
#if __has_builtin(__builtin_amdgcn_exp2f)
  return __builtin_amdgcn_exp2f(x);
#else
  return __expf(x * 0.6931471805599453f);
#endif
}
__device__ __forceinline__ bf16x8 ld_frag(const unsigned short* p){
  union { uint4 u; bf16x8 b; } cv;
  cv.u = *(const uint4*)p;
  return cv.b;
}
__device__ __forceinline__ f32x4 mf(bf16x8 a, bf16x8 b, f32x4 c){
  return __builtin_amdgcn_mfma_f32_16x16x32_bf16(a, b, c, 0, 0, 0);
}
__device__ __forceinline__ f32x16 mf32(bf16x8 a, bf16x8 b, f32x16 c){
  return __builtin_amdgcn_mfma_f32_32x32x16_bf16(a, b, c, 0, 0, 0);
}
// K tile swizzle: 64 rows x 128 cols (shorts), 16B-group XOR
__device__ __forceinline__ int swiK(int row, int col){
  return row*128 + (col ^ ((((row)&15) ^ ((row>>1)&8)) << 3));
}
// Vt tile swizzle: 128 rows x 64 cols (shorts)
__device__ __forceinline__ int swiV(int row, int col){
  return row*64 + (col ^ (((row)&7) << 3));
}

// ---------------- K1: fused QKV proj GEMM (dbuf, 1 barrier/step) + mswz -----
// grid (168,4,4): bx<40 -> GEMM (n0=bx*64, m0=by*64, kz=bz);
//                 bx>=40 -> mask pre-swizzle block (2048 total).
__global__ __launch_bounds__(256) void k_gemm_qkv(
    const float* __restrict__ A,              // hidden_states f32 [256][2048]
    const float* __restrict__ qw, const float* __restrict__ kw, const float* __restrict__ vw,
    const float* __restrict__ qbv, const float* __restrict__ kbv, const float* __restrict__ vbv,
    float* __restrict__ rawp,
    const float* __restrict__ mask, float* __restrict__ msw)
{
  __shared__ unsigned short As[2][64][56];
  __shared__ unsigned short Bs[2][64][56];
  const int bx = blockIdx.x;
  if(bx >= 40){
    // ---- mask: (m - C)*log2e -> fragment layout ----
    const int mb = (bx-40) + 128*(blockIdx.y + 4*blockIdx.z);
    const int g = mb*256 + threadIdx.x;
    const int b = g >> 16, q = (g>>11)&31, c4 = g & 2047;
    const int kv = c4*4;
    const int sp = kv>>9, tt = (kv>>6)&7, kvt = (kv>>5)&1, r4 = (kv>>3)&3, hi = (kv>>2)&1;
    const int lane = q + 32*hi;
    float4 v = *(const float4*)(mask + ((long)b*S_ + q)*KV_ + kv);
    v.x = (v.x - CFIX_)*LOG2E_; v.y = (v.y - CFIX_)*LOG2E_;
    v.z = (v.z - CFIX_)*LOG2E_; v.w = (v.w - CFIX_)*LOG2E_;
    const long dst = ((((long)(b*NSP+sp)*NT_ + tt)*64 + lane)*8 + kvt*4 + r4);
    *(float4*)(msw + dst*4) = v;
    return;
  }
  const int n0 = bx*64, m0 = blockIdx.y*64, kz = blockIdx.z;
  const int kb = kz*512;
  const float* W; const float* bias; int ldw, wc0;
  if(n0 < 2048)      { W=qw; bias=qbv; ldw=2048; wc0=n0; }
  else if(n0 < 2304) { W=kw; bias=kbv; ldw=256;  wc0=n0-2048; }
  else               { W=vw; bias=vbv; ldw=256;  wc0=n0-2304; }
  const int t = threadIdx.x, lane = t&63, wid = t>>6;
  const int wr = wid>>1, wc = wid&1, l15 = lane&15, lq = lane>>4;
  const int ar = t>>2,  ac = (t&3)*8;
  const int bk = t>>5,  bn = (t&31)*2;
  float4 a0r, a1r; float2 wvr[4];
  auto loadAB = [&](int k0){
    a0r = *(const float4*)(A + (m0+ar)*2048 + k0 + ac);
    a1r = *(const float4*)(A + (m0+ar)*2048 + k0 + ac + 4);
    #pragma unroll
    for(int p=0;p<4;p++)
      wvr[p] = *(const float2*)(W + (long)(k0 + bk + p*8)*ldw + wc0 + bn);
  };
  auto writeAB = [&](int buf){
    uint4 w4; w4.x=cvtpk(a0r.x,a0r.y); w4.y=cvtpk(a0r.z,a0r.w);
              w4.z=cvtpk(a1r.x,a1r.y); w4.w=cvtpk(a1r.z,a1r.w);
    *(uint4*)(&As[buf][ar][ac]) = w4;
    #pragma unroll
    for(int p=0;p<4;p++){
      Bs[buf][bn  ][bk+p*8] = f2b(wvr[p].x);
      Bs[buf][bn+1][bk+p*8] = f2b(wvr[p].y);
    }
  };
  loadAB(kb); writeAB(0);
  __syncthreads();
  f32x4 acc[2][2] = {};
  for(int i=0;i<16;i++){
    const int cur = i&1;
    if(i<15) loadAB(kb + (i+1)*32);
    const bf16x8 a0 = ld_frag(&As[cur][wr*32      + l15][lq*8]);
    const bf16x8 a1 = ld_frag(&As[cur][wr*32 + 16 + l15][lq*8]);
    const bf16x8 b0 = ld_frag(&Bs[cur][wc*32      + l15][lq*8]);
    const bf16x8 b1 = ld_frag(&Bs[cur][wc*32 + 16 + l15][lq*8]);
    acc[0][0] = mf(a0,b0,acc[0][0]);
    acc[0][1] = mf(a0,b1,acc[0][1]);
    acc[1][0] = mf(a1,b0,acc[1][0]);
    acc[1][1] = mf(a1,b1,acc[1][1]);
    if(i<15) writeAB(cur^1);
    __syncthreads();
  }
  float* out = rawp + (long)kz*M_*NQKV;
  #pragma unroll
  for(int mi=0;mi<2;mi++)
    #pragma unroll
    for(int nj=0;nj<2;nj++){
      const int col = n0 + wc*32 + nj*16 + l15;
      const float bv = kz ? 0.f : bias[wc0 + wc*32 + nj*16 + l15];
      #pragma unroll
      for(int rr=0;rr<4;rr++){
        const int row = m0 + wr*32 + mi*16 + lq*4 + rr;
        out[row*NQKV + col] = acc[mi][nj][rr] + bv;
      }
    }
}

// ---------------- K2: sum 4 K-quarters + RoPE + pack ----------------
__global__ __launch_bounds__(128) void k_rope(
    const float* __restrict__ rawp, const float* __restrict__ cosb, const float* __restrict__ sinb,
    unsigned short* __restrict__ Qb, float* __restrict__ KnF, float* __restrict__ VnF)
{
  const int r = blockIdx.x, hh = blockIdx.y, d = threadIdx.x;
  const int b = r>>5, s = r&31;
  const long MN = (long)M_*NQKV;
  const float cv = cosb[(b*S_+s)*HD_ + d];
  const float sv = sinb[(b*S_+s)*HD_ + d];
  const int dp = (d<64)? d+64 : d-64;
  #define RAW4(c) (rawp[r*NQKV+(c)] + rawp[MN+r*NQKV+(c)] + rawp[2*MN+r*NQKV+(c)] + rawp[3*MN+r*NQKV+(c)])
  if(hh < 16){
    const float x  = RAW4(hh*HD_ + d);
    const float xo = RAW4(hh*HD_ + dp);
    const float y  = x*cv + ((d<64)? -xo : xo)*sv;
    const int kvh = hh>>3, g = hh&7;
    Qb[((long)(b*NKV_+kvh)*M_ + g*S_ + s)*HD_ + d] = f2b(y);
  } else if(hh < 18){
    const int kvh = hh-16;
    const float x  = RAW4(2048 + kvh*HD_ + d);
    const float xo = RAW4(2048 + kvh*HD_ + dp);
    KnF[((long)(b*NKV_+kvh)*S_ + s)*HD_ + d] = x*cv + ((d<64)? -xo : xo)*sv;
  } else {
    const int kvh = hh-18;
    VnF[((long)(b*NKV_+kvh)*S_ + s)*HD_ + d] = RAW4(2304 + kvh*HD_ + d);
  }
  #undef RAW4
}

// ---------------- K3: split-KV attention (R11 structure + exp2 softmax) -----
// grid (sp=16, kvh=2, b=8) = 256 blocks; 512 thr = 8 waves; wave owns 32 q.
// 2-buf double-buffer, one barrier per subtile; fixed-C softmax in 2^x domain.
__global__ __launch_bounds__(512, 2) void k_attn(
    const unsigned short* __restrict__ Qb,
    const float* __restrict__ KnF, const float* __restrict__ VnF,
    const float* __restrict__ kc, const float* __restrict__ vc,
    const float* __restrict__ msw, const int* __restrict__ rpp,
    unsigned short* __restrict__ num, float* __restrict__ lbuf)
{
  __shared__ __align__(16) unsigned short lds[2][2][KT_*128]; // [buf][K|Vt] 64KB
  const int sp = blockIdx.x, kvh = blockIdx.y, b = blockIdx.z;
  const int bk = b*NKV_ + kvh;
  const int rp = *rpp;
  const int t = threadIdx.x, lane = t&63, wid = t>>6;
  const int l31 = lane&31, hi = lane>>5;
  const int kvbase = sp*(KV_/NSP);
  const int krow = t>>3, kc0 = (t&7)*16;
  const int vhd  = t&127, vkq = t>>7;
  const int cbsK = (hi*8) ^ ((((l31)&15) ^ ((l31>>1)&8)) << 3);
  const int cbsV = (hi*8) ^ (((l31)&7) << 3);
  const int rowK = l31*128, rowV = l31*64;
  const int wk0 = swiK(krow, kc0), wk1 = swiK(krow, kc0+8);
  const int wv0 = swiV(vhd, vkq*16), wv1 = swiV(vhd, vkq*16+8);

  bf16x8 qf[8];
  { const unsigned short* qp = Qb + ((long)bk*M_ + wid*32 + l31)*HD_;
    #pragma unroll
    for(int ks=0;ks<8;ks++) qf[ks] = ld_frag(qp + ks*16 + hi*8); }

  float4 vK4[4];
  float  vV[16];
  float4 vM[8];
  const float4* mbase = (const float4*)msw + ((long)(b*NSP+sp)*NT_)*64*8 + lane*8;

  auto loadK = [&](int tt){
    const int kvr = kvbase + tt*KT_ + krow;
    const float* kp = (kvr>=rp && kvr<rp+S_)
        ? (KnF + ((long)bk*S_ + (kvr-rp))*HD_ + kc0)
        : (kc  + ((long)bk*KV_ + kvr)*HD_ + kc0);
    #pragma unroll
    for(int i=0;i<4;i++) vK4[i] = *(const float4*)(kp + i*4);
  };
  auto loadV = [&](int tt){
    #pragma unroll
    for(int m=0;m<16;m++){
      const int kvr = kvbase + tt*KT_ + vkq*16 + m;
      const float* vp = (kvr>=rp && kvr<rp+S_)
          ? (VnF + ((long)bk*S_ + (kvr-rp))*HD_)
          : (vc  + ((long)bk*KV_ + kvr)*HD_);
      vV[m] = vp[vhd];
    }
  };
  auto loadM = [&](int tt){
    const float4* mp = mbase + (long)tt*64*8;
    #pragma unroll
    for(int j=0;j<8;j++) vM[j] = mp[j];
  };
  auto writeK = [&](int bb){
    unsigned short* Sb = &lds[bb][0][0];
    uint4 w4;
    w4.x = cvtpk(vK4[0].x, vK4[0].y);  w4.y = cvtpk(vK4[0].z, vK4[0].w);
    w4.z = cvtpk(vK4[1].x, vK4[1].y);  w4.w = cvtpk(vK4[1].z, vK4[1].w);
    *(uint4*)(Sb + wk0) = w4;
    w4.x = cvtpk(vK4[2].x, vK4[2].y);  w4.y = cvtpk(vK4[2].z, vK4[2].w);
    w4.z = cvtpk(vK4[3].x, vK4[3].y);  w4.w = cvtpk(vK4[3].z, vK4[3].w);
    *(uint4*)(Sb + wk1) = w4;
  };
  auto writeV = [&](int bb){
    unsigned short* Sb = &lds[bb][1][0];
    uint4 w4;
    w4.x = cvtpk(vV[0], vV[1]);   w4.y = cvtpk(vV[2], vV[3]);
    w4.z = cvtpk(vV[4], vV[5]);   w4.w = cvtpk(vV[6], vV[7]);
    *(uint4*)(Sb + wv0) = w4;
    w4.x = cvtpk(vV[8], vV[9]);   w4.y = cvtpk(vV[10], vV[11]);
    w4.z = cvtpk(vV[12], vV[13]); w4.w = cvtpk(vV[14], vV[15]);
    *(uint4*)(Sb + wv1) = w4;
  };

  loadK(0); loadV(0);
  writeK(0); writeV(0);
  __syncthreads();

  f32x16 oc[4] = {};
  float l_run = 0.f;

  for(int tt=0; tt<NT_; tt++){
    const int cur = tt&1;
    loadM(tt);
    if(tt<NT_-1){ loadK(tt+1); loadV(tt+1); }
    f32x16 sc[2] = {};
    { const unsigned short* Sk = &lds[cur][0][0];
      __builtin_amdgcn_s_setprio(1);
      #pragma unroll
      for(int ks=0;ks<8;ks++){
        #pragma unroll
        for(int kvt=0;kvt<2;kvt++)
          sc[kvt] = mf32(ld_frag(Sk + rowK + kvt*4096 + (cbsK ^ (ks*16))), qf[ks], sc[kvt]);
      }
      __builtin_amdgcn_s_setprio(0);
    }
    float psum = 0.f;
    #pragma unroll
    for(int kvt=0;kvt<2;kvt++){
      #pragma unroll
      for(int r4=0;r4<4;r4++){
        const float4 mk = vM[kvt*4+r4];
        const float p0 = fexp2(fmaf(sc[kvt][r4*4+0], SCALE2_, mk.x));
        const float p1 = fexp2(fmaf(sc[kvt][r4*4+1], SCALE2_, mk.y));
        const float p2 = fexp2(fmaf(sc[kvt][r4*4+2], SCALE2_, mk.z));
        const float p3 = fexp2(fmaf(sc[kvt][r4*4+3], SCALE2_, mk.w));
        sc[kvt][r4*4+0]=p0; sc[kvt][r4*4+1]=p1;
        sc[kvt][r4*4+2]=p2; sc[kvt][r4*4+3]=p3;
        psum += (p0+p1)+(p2+p3);
      }
    }
    l_run += psum;
    unsigned w_[2][4][2];
    #pragma unroll
    for(int kvt=0;kvt<2;kvt++)
      #pragma unroll
      for(int r4=0;r4<4;r4++){
        w_[kvt][r4][0] = cvtpk(sc[kvt][r4*4+0], sc[kvt][r4*4+1]);
        w_[kvt][r4][1] = cvtpk(sc[kvt][r4*4+2], sc[kvt][r4*4+3]);
      }
    { const unsigned short* Sv = &lds[cur][1][0];
      __builtin_amdgcn_s_setprio(1);
      #pragma unroll
      for(int kvs=0;kvs<4;kvs++){
        const int kvt = kvs>>1, k2 = (kvs&1)*2;
        const unsigned wa0 = w_[kvt][k2  ][0], wa1 = w_[kvt][k2  ][1];
        const unsigned wb0 = w_[kvt][k2+1][0], wb1 = w_[kvt][k2+1][1];
        const unsigned own0 = hi? wb0:wa0, own1 = hi? wb1:wa1;
        const unsigned snd0 = hi? wa0:wb0, snd1 = hi? wa1:wb1;
        const unsigned rcv0 = __shfl_xor(snd0, 32, 64);
        const unsigned rcv1 = __shfl_xor(snd1, 32, 64);
        union{ unsigned u[4]; bf16x8 v; } ap;
        ap.u[0] = hi? rcv0:own0;  ap.u[1] = hi? rcv1:own1;
        ap.u[2] = hi? own0:rcv0;  ap.u[3] = hi? own1:rcv1;
        #pragma unroll
        for(int ht=0;ht<4;ht++)
          oc[ht] = mf32(ap.v, ld_frag(Sv + rowV + ht*2048 + (cbsV ^ (kvs*16))), oc[ht]);
      }
      __builtin_amdgcn_s_setprio(0);
    }
    if(tt<NT_-1){ writeK(cur^1); writeV(cur^1); }
    __syncthreads();
  }

  const float l_tot = l_run + __shfl_xor(l_run, 32, 64);
  if(lane < 32){
    lbuf[((long)bk*NSP + sp)*M_ + wid*32 + lane] = l_tot;
  }
  unsigned short* np_ = num + (((long)bk*NSP + sp)*M_ + wid*32)*HD_;
  #pragma unroll
  for(int ht=0;ht<4;ht++)
    #pragma unroll
    for(int r4=0;r4<4;r4++)
      #pragma unroll
      for(int rr=0;rr<4;rr++){
        const int q = rr + 8*r4 + 4*hi;
        np_[(long)q*HD_ + ht*32 + l31] = f2b(oc[ht][r4*4+rr]);
      }
}

// ---------------- K4: combine split-KV partials (uniform weights, uint lds) -
__global__ __launch_bounds__(64) void k_comb(
    const unsigned short* __restrict__ num, const float* __restrict__ lbuf,
    unsigned short* __restrict__ attnb)
{
  const int q = blockIdx.x, kvh = blockIdx.y, b = blockIdx.z, d2 = threadIdx.x;
  const int bk = b*NKV_ + kvh;
  float den = 0.f, a0 = 0.f, a1 = 0.f;
  #pragma unroll
  for(int c=0;c<NSP;c++){
    const long ix = ((long)bk*NSP + c)*M_ + q;
    den += lbuf[ix];
    const unsigned u = *(const unsigned*)(num + ix*HD_ + 2*d2);
    a0 += b2f((unsigned short)(u & 0xffffu));
    a1 += b2f((unsigned short)(u >> 16));
  }
  const float r = 1.0f / den;
  const int g = q>>5, s = q&31, h = kvh*G_ + g;
  *(unsigned*)(attnb + ((long)(b*S_+s))*2048 + h*HD_ + 2*d2) = cvtpk(a0*r, a1*r);
}

// ---------------- K5: output projection GEMM, split-K=4, dbuf ----------------
__global__ __launch_bounds__(256) void k_gemm_o(
    const unsigned short* __restrict__ A,
    const float* __restrict__ W,
    float* __restrict__ owsp)
{
  __shared__ unsigned short As[2][64][56];
  __shared__ unsigned short Bs[2][64][56];
  const int n0 = blockIdx.x*64, m0 = blockIdx.y*64, kz = blockIdx.z;
  const int kb = kz*512;
  const int t = threadIdx.x, lane = t&63, wid = t>>6;
  const int wr = wid>>1, wc = wid&1, l15 = lane&15, lq = lane>>4;
  const int ar = t>>2,  ac = (t&3)*8;
  const int bk = t>>5,  bn = (t&31)*2;
  uint4 a4r; float2 wvr[4];
  auto loadAB = [&](int k0){
    a4r = *(const uint4*)(A + (m0+ar)*2048 + k0 + ac);
    #pragma unroll
    for(int p=0;p<4;p++)
      wvr[p] = *(const float2*)(W + (long)(k0 + bk + p*8)*2048 + n0 + bn);
  };
  auto writeAB = [&](int buf){
    *(uint4*)(&As[buf][ar][ac]) = a4r;
    #pragma unroll
    for(int p=0;p<4;p++){
      Bs[buf][bn  ][bk+p*8] = f2b(wvr[p].x);
      Bs[buf][bn+1][bk+p*8] = f2b(wvr[p].y);
    }
  };
  loadAB(kb); writeAB(0);
  __syncthreads();
  f32x4 acc[2][2] = {};
  for(int i=0;i<16;i++){
    const int cur = i&1;
    if(i<15) loadAB(kb + (i+1)*32);
    const bf16x8 a0 = ld_frag(&As[cur][wr*32      + l15][lq*8]);
    const bf16x8 a1 = ld_frag(&As[cur][wr*32 + 16 + l15][lq*8]);
    const bf16x8 b0 = ld_frag(&Bs[cur][wc*32      + l15][lq*8]);
    const bf16x8 b1 = ld_frag(&Bs[cur][wc*32 + 16 + l15][lq*8]);
    acc[0][0] = mf(a0,b0,acc[0][0]);
    acc[0][1] = mf(a0,b1,acc[0][1]);
    acc[1][0] = mf(a1,b0,acc[1][0]);
    acc[1][1] = mf(a1,b1,acc[1][1]);
    if(i<15) writeAB(cur^1);
    __syncthreads();
  }
  float* out = owsp + (long)kz*M_*2048;
  #pragma unroll
  for(int mi=0;mi<2;mi++)
    #pragma unroll
    for(int nj=0;nj<2;nj++){
      const int col = n0 + wc*32 + nj*16 + l15;
      #pragma unroll
      for(int rr=0;rr<4;rr++){
        const int row = m0 + wr*32 + mi*16 + lq*4 + rr;
        out[row*2048 + col] = acc[mi][nj][rr];
      }
    }
}

// ---------------- K6: fold the four O K-quarters ----------------
__global__ __launch_bounds__(256) void k_ored(const float* __restrict__ a,
                                              float* __restrict__ out){
  const int i = (blockIdx.x*256 + threadIdx.x)*4;
  const long MN = (long)M_*2048;
  const float4 x = *(const float4*)(a + i);
  const float4 y = *(const float4*)(a + MN + i);
  const float4 z = *(const float4*)(a + 2*MN + i);
  const float4 w = *(const float4*)(a + 3*MN + i);
  float4 o; o.x=(x.x+y.x)+(z.x+w.x); o.y=(x.y+y.y)+(z.y+w.y);
            o.z=(x.z+y.z)+(z.z+w.z); o.w=(x.w+y.w)+(z.w+w.w);
  *(float4*)(out + i) = o;
}

extern "C" void kernel_launch(void* const* d_in, const int* in_sizes, int n_in,
                              void* d_out, int out_size, void* d_ws, size_t ws_size,
                              hipStream_t stream){
  (void)in_sizes; (void)n_in; (void)out_size; (void)ws_size;
  const float* hs   = (const float*)d_in[0];
  const float* cosb = (const float*)d_in[1];
  const float* sinb = (const float*)d_in[2];
  const float* kc   = (const float*)d_in[3];
  const float* vc   = (const float*)d_in[4];
  const float* mask = (const float*)d_in[5];
  const int*   rp   = (const int*)  d_in[6];
  const float* qw   = (const float*)d_in[7];
  const float* qb   = (const float*)d_in[8];
  const float* kw   = (const float*)d_in[9];
  const float* kb   = (const float*)d_in[10];
  const float* vw   = (const float*)d_in[11];
  const float* vb   = (const float*)d_in[12];
  const float* ow   = (const float*)d_in[13];
  char* ws = (char*)d_ws;
  // ws layout (bytes)
  float*          rawp  = (float*)         (ws + 0);          // 10,485,760 (4 K-quarters)
  unsigned short* Qb    = (unsigned short*)(ws + 10485760);   //  1,048,576
  float*          KnF   = (float*)         (ws + 11534336);   //    262,144
  float*          VnF   = (float*)         (ws + 11796480);   //    262,144
  unsigned short* attnb = (unsigned short*)(ws + 12058624);   //  1,048,576
  float*          lbuf  = (float*)         (ws + 13107200);   //    262,144
  unsigned short* num   = (unsigned short*)(ws + 13369344);   // 16,777,216
  float*          owsp  = (float*)         (ws + 30146560);   //  8,388,608 (4 quarters)
  float*          msw   = (float*)         (ws + 38535168);   //  8,388,608 (end ~46.9 MB)
  float* outp = (float*)d_out;

  k_gemm_qkv<<<dim3(168,4,4),    dim3(256),  0, stream>>>(hs, qw,kw,vw, qb,kb,vb, rawp, mask, msw);
  k_rope    <<<dim3(256,20),     dim3(128),  0, stream>>>(rawp, cosb, sinb, Qb, KnF, VnF);
  k_attn    <<<dim3(NSP,2,8),    dim3(512),  0, stream>>>(Qb, KnF, VnF, kc, vc, msw, rp, num, lbuf);
  k_comb    <<<dim3(256,2,8),    dim3(64),   0, stream>>>(num, lbuf, attnb);
  k_gemm_o  <<<dim3(32,4,4),     dim3(256),  0, stream>>>(attnb, ow, owsp);
  k_ored    <<<dim3(512),        dim3(256),  0, stream>>>(owsp, outp);
}

// Round 18
// 97.820 us; speedup vs baseline: 1.0373x; 1.0373x over previous
//
#include <hip/hip_runtime.h>
#include <hip/hip_bf16.h>

#define B_    8
#define S_    32
#define H_    2048
#define NH_   16
#define NKV_  2
#define HD_   128
#define KV_   8192
#define G_    8
#define M_    256      /* B*S */
#define NQKV  2560     /* fused proj N: 2048 q | 256 k | 256 v */
#define NSP   16       /* kv splits */
#define KT_   64       /* kv subtile */
#define NT_   8        /* subtiles per block = KV_/NSP/KT_ */
#define SCALE_ 0.08838834764831845f
#define CFIX_  8.0f
#define LOG2E_ 1.4426950408889634f
#define SCALE2_ (SCALE_*LOG2E_)

typedef __bf16 bf16x8 __attribute__((ext_vector_type(8)));
typedef float  f32x4  __attribute__((ext_vector_type(4)));
typedef float  f32x16 __attribute__((ext_vector_type(16)));

__device__ __forceinline__ unsigned short f2b(float f){
  unsigned u = __float_as_uint(f);
  u = u + 0x7FFFu + ((u>>16)&1u);           // RNE f32->bf16
  return (unsigned short)(u>>16);
}
__device__ __forceinline__ float b2f(unsigned short h){
  return __uint_as_float(((unsigned)h)<<16);
}
// HW packed f32->bf16 pair (T12 recipe; no builtin on gfx950)
__device__ __forceinline__ unsigned cvtpk(float lo, float hi){
  unsigned r;
  asm("v_cvt_pk_bf16_f32 %0, %1, %2" : "=v"(r) : "v"(lo), "v"(hi));
  return r;
}
// raw v_exp_f32 (2^x)
__device__ __forceinline__ float fexp2(float x){
#if __has_builtin(__builtin_amdgcn_exp2f)
  return __builtin_amdgcn_exp2f(x);
#else
  return __expf(x * 0.6931471805599453f);
#endif
}
__device__ __forceinline__ bf16x8 ld_frag(const unsigned short* p){
  union { uint4 u; bf16x8 b; } cv;
  cv.u = *(const uint4*)p;
  return cv.b;
}
__device__ __forceinline__ f32x4 mf(bf16x8 a, bf16x8 b, f32x4 c){
  return __builtin_amdgcn_mfma_f32_16x16x32_bf16(a, b, c, 0, 0, 0);
}
__device__ __forceinline__ f32x16 mf32(bf16x8 a, bf16x8 b, f32x16 c){
  return __builtin_amdgcn_mfma_f32_32x32x16_bf16(a, b, c, 0, 0, 0);
}
// K tile swizzle: 64 rows x 128 cols (shorts), 16B-group XOR
__device__ __forceinline__ int swiK(int row, int col){
  return row*128 + (col ^ ((((row)&15) ^ ((row>>1)&8)) << 3));
}
// Vt tile swizzle: 128 rows x 64 cols (shorts)
__device__ __forceinline__ int swiV(int row, int col){
  return row*64 + (col ^ (((row)&7) << 3));
}

// ---------------- K1: fused QKV projection GEMM, split-K=4, inline f32->bf16
__global__ __launch_bounds__(256) void k_gemm_qkv(
    const float* __restrict__ A,              // hidden_states f32 [256][2048]
    const float* __restrict__ qw, const float* __restrict__ kw, const float* __restrict__ vw,
    const float* __restrict__ qbv, const float* __restrict__ kbv, const float* __restrict__ vbv,
    float* __restrict__ rawp)
{
  __shared__ unsigned short As[64][56];
  __shared__ unsigned short Bs[64][56];
  const int n0 = blockIdx.x*64, m0 = blockIdx.y*64, kz = blockIdx.z;
  const float* W; const float* bias; int ldw, wc0;
  if(n0 < 2048)      { W=qw; bias=qbv; ldw=2048; wc0=n0; }
  else if(n0 < 2304) { W=kw; bias=kbv; ldw=256;  wc0=n0-2048; }
  else               { W=vw; bias=vbv; ldw=256;  wc0=n0-2304; }
  const int t = threadIdx.x, lane = t&63, wid = t>>6;
  const int wr = wid>>1, wc = wid&1, l15 = lane&15, lq = lane>>4;
  const int ar = t>>2,  ac = (t&3)*8;
  const int bk = t>>5,  bn = (t&31)*2;
  f32x4 acc[2][2] = {};
  for(int k0 = kz*512; k0 < kz*512 + 512; k0 += 32){
    __syncthreads();
    { const float4 a0 = *(const float4*)(A + (m0+ar)*2048 + k0 + ac);
      const float4 a1 = *(const float4*)(A + (m0+ar)*2048 + k0 + ac + 4);
      uint4 w4; w4.x=cvtpk(a0.x,a0.y); w4.y=cvtpk(a0.z,a0.w);
                w4.z=cvtpk(a1.x,a1.y); w4.w=cvtpk(a1.z,a1.w);
      *(uint4*)(&As[ar][ac]) = w4; }
    #pragma unroll
    for(int p=0;p<4;p++){
      const int kk = bk + p*8;
      const float2 wv = *(const float2*)(W + (long)(k0+kk)*ldw + wc0 + bn);
      Bs[bn  ][kk] = f2b(wv.x);
      Bs[bn+1][kk] = f2b(wv.y);
    }
    __syncthreads();
    const bf16x8 a0 = ld_frag(&As[wr*32      + l15][lq*8]);
    const bf16x8 a1 = ld_frag(&As[wr*32 + 16 + l15][lq*8]);
    const bf16x8 b0 = ld_frag(&Bs[wc*32      + l15][lq*8]);
    const bf16x8 b1 = ld_frag(&Bs[wc*32 + 16 + l15][lq*8]);
    acc[0][0] = mf(a0,b0,acc[0][0]);
    acc[0][1] = mf(a0,b1,acc[0][1]);
    acc[1][0] = mf(a1,b0,acc[1][0]);
    acc[1][1] = mf(a1,b1,acc[1][1]);
  }
  float* out = rawp + (long)kz*M_*NQKV;
  #pragma unroll
  for(int mi=0;mi<2;mi++)
    #pragma unroll
    for(int nj=0;nj<2;nj++){
      const int col = n0 + wc*32 + nj*16 + l15;
      const float bv = kz ? 0.f : bias[wc0 + wc*32 + nj*16 + l15];
      #pragma unroll
      for(int rr=0;rr<4;rr++){
        const int row = m0 + wr*32 + mi*16 + lq*4 + rr;
        out[row*NQKV + col] = acc[mi][nj][rr] + bv;
      }
    }
}

// ---------------- K2: sum 4 K-quarters + RoPE + pack ----------------
__global__ __launch_bounds__(128) void k_rope(
    const float* __restrict__ rawp, const float* __restrict__ cosb, const float* __restrict__ sinb,
    unsigned short* __restrict__ Qb, float* __restrict__ KnF, float* __restrict__ VnF)
{
  const int r = blockIdx.x, hh = blockIdx.y, d = threadIdx.x;
  const int b = r>>5, s = r&31;
  const long MN = (long)M_*NQKV;
  const float cv = cosb[(b*S_+s)*HD_ + d];
  const float sv = sinb[(b*S_+s)*HD_ + d];
  const int dp = (d<64)? d+64 : d-64;
  #define RAW4(c) (rawp[r*NQKV+(c)] + rawp[MN+r*NQKV+(c)] + rawp[2*MN+r*NQKV+(c)] + rawp[3*MN+r*NQKV+(c)])
  if(hh < 16){
    const float x  = RAW4(hh*HD_ + d);
    const float xo = RAW4(hh*HD_ + dp);
    const float y  = x*cv + ((d<64)? -xo : xo)*sv;
    const int kvh = hh>>3, g = hh&7;
    Qb[((long)(b*NKV_+kvh)*M_ + g*S_ + s)*HD_ + d] = f2b(y);
  } else if(hh < 18){
    const int kvh = hh-16;
    const float x  = RAW4(2048 + kvh*HD_ + d);
    const float xo = RAW4(2048 + kvh*HD_ + dp);
    KnF[((long)(b*NKV_+kvh)*S_ + s)*HD_ + d] = x*cv + ((d<64)? -xo : xo)*sv;
  } else {
    const int kvh = hh-18;
    VnF[((long)(b*NKV_+kvh)*S_ + s)*HD_ + d] = RAW4(2304 + kvh*HD_ + d);
  }
  #undef RAW4
}

// ---------------- K2c: (mask - C)*log2e -> fragment-layout pre-swizzle ------
__global__ __launch_bounds__(256) void k_mswz(const float* __restrict__ mask,
                                              float* __restrict__ msw){
  const int g = blockIdx.x*256 + threadIdx.x;       // one float4 per thread
  const int b = g >> 16, q = (g>>11)&31, c4 = g & 2047;
  const int kv = c4*4;
  const int sp = kv>>9, tt = (kv>>6)&7, kvt = (kv>>5)&1, r4 = (kv>>3)&3, hi = (kv>>2)&1;
  const int lane = q + 32*hi;
  float4 v = *(const float4*)(mask + ((long)b*S_ + q)*KV_ + kv);
  v.x = (v.x - CFIX_)*LOG2E_; v.y = (v.y - CFIX_)*LOG2E_;
  v.z = (v.z - CFIX_)*LOG2E_; v.w = (v.w - CFIX_)*LOG2E_;
  const long dst = ((((long)(b*NSP+sp)*NT_ + tt)*64 + lane)*8 + kvt*4 + r4);
  *(float4*)(msw + dst*4) = v;
}

// ---------------- K3: split-KV attention (R11 structure + exp2 softmax) -----
// grid (sp=16, kvh=2, b=8) = 256 blocks; 512 thr = 8 waves; wave owns 32 q.
// 2-buf double-buffer, one barrier per subtile; fixed-C softmax in 2^x domain.
__global__ __launch_bounds__(512, 2) void k_attn(
    const unsigned short* __restrict__ Qb,
    const float* __restrict__ KnF, const float* __restrict__ VnF,
    const float* __restrict__ kc, const float* __restrict__ vc,
    const float* __restrict__ msw, const int* __restrict__ rpp,
    unsigned short* __restrict__ num, float* __restrict__ lbuf)
{
  __shared__ __align__(16) unsigned short lds[2][2][KT_*128]; // [buf][K|Vt] 64KB
  const int sp = blockIdx.x, kvh = blockIdx.y, b = blockIdx.z;
  const int bk = b*NKV_ + kvh;
  const int rp = *rpp;
  const int t = threadIdx.x, lane = t&63, wid = t>>6;
  const int l31 = lane&31, hi = lane>>5;
  const int kvbase = sp*(KV_/NSP);
  const int krow = t>>3, kc0 = (t&7)*16;
  const int vhd  = t&127, vkq = t>>7;
  const int cbsK = (hi*8) ^ ((((l31)&15) ^ ((l31>>1)&8)) << 3);
  const int cbsV = (hi*8) ^ (((l31)&7) << 3);
  const int rowK = l31*128, rowV = l31*64;
  const int wk0 = swiK(krow, kc0), wk1 = swiK(krow, kc0+8);
  const int wv0 = swiV(vhd, vkq*16), wv1 = swiV(vhd, vkq*16+8);

  bf16x8 qf[8];
  { const unsigned short* qp = Qb + ((long)bk*M_ + wid*32 + l31)*HD_;
    #pragma unroll
    for(int ks=0;ks<8;ks++) qf[ks] = ld_frag(qp + ks*16 + hi*8); }

  float4 vK4[4];
  float  vV[16];
  float4 vM[8];
  const float4* mbase = (const float4*)msw + ((long)(b*NSP+sp)*NT_)*64*8 + lane*8;

  auto loadK = [&](int tt){
    const int kvr = kvbase + tt*KT_ + krow;
    const float* kp = (kvr>=rp && kvr<rp+S_)
        ? (KnF + ((long)bk*S_ + (kvr-rp))*HD_ + kc0)
        : (kc  + ((long)bk*KV_ + kvr)*HD_ + kc0);
    #pragma unroll
    for(int i=0;i<4;i++) vK4[i] = *(const float4*)(kp + i*4);
  };
  auto loadV = [&](int tt){
    #pragma unroll
    for(int m=0;m<16;m++){
      const int kvr = kvbase + tt*KT_ + vkq*16 + m;
      const float* vp = (kvr>=rp && kvr<rp+S_)
          ? (VnF + ((long)bk*S_ + (kvr-rp))*HD_)
          : (vc  + ((long)bk*KV_ + kvr)*HD_);
      vV[m] = vp[vhd];
    }
  };
  auto loadM = [&](int tt){
    const float4* mp = mbase + (long)tt*64*8;
    #pragma unroll
    for(int j=0;j<8;j++) vM[j] = mp[j];
  };
  auto writeK = [&](int bb){
    unsigned short* Sb = &lds[bb][0][0];
    uint4 w4;
    w4.x = cvtpk(vK4[0].x, vK4[0].y);  w4.y = cvtpk(vK4[0].z, vK4[0].w);
    w4.z = cvtpk(vK4[1].x, vK4[1].y);  w4.w = cvtpk(vK4[1].z, vK4[1].w);
    *(uint4*)(Sb + wk0) = w4;
    w4.x = cvtpk(vK4[2].x, vK4[2].y);  w4.y = cvtpk(vK4[2].z, vK4[2].w);
    w4.z = cvtpk(vK4[3].x, vK4[3].y);  w4.w = cvtpk(vK4[3].z, vK4[3].w);
    *(uint4*)(Sb + wk1) = w4;
  };
  auto writeV = [&](int bb){
    unsigned short* Sb = &lds[bb][1][0];
    uint4 w4;
    w4.x = cvtpk(vV[0], vV[1]);   w4.y = cvtpk(vV[2], vV[3]);
    w4.z = cvtpk(vV[4], vV[5]);   w4.w = cvtpk(vV[6], vV[7]);
    *(uint4*)(Sb + wv0) = w4;
    w4.x = cvtpk(vV[8], vV[9]);   w4.y = cvtpk(vV[10], vV[11]);
    w4.z = cvtpk(vV[12], vV[13]); w4.w = cvtpk(vV[14], vV[15]);
    *(uint4*)(Sb + wv1) = w4;
  };

  loadK(0); loadV(0);
  writeK(0); writeV(0);
  __syncthreads();

  f32x16 oc[4] = {};
  float l_run = 0.f;

  for(int tt=0; tt<NT_; tt++){
    const int cur = tt&1;
    loadM(tt);
    if(tt<NT_-1){ loadK(tt+1); loadV(tt+1); }
    f32x16 sc[2] = {};
    { const unsigned short* Sk = &lds[cur][0][0];
      __builtin_amdgcn_s_setprio(1);
      #pragma unroll
      for(int ks=0;ks<8;ks++){
        #pragma unroll
        for(int kvt=0;kvt<2;kvt++)
          sc[kvt] = mf32(ld_frag(Sk + rowK + kvt*4096 + (cbsK ^ (ks*16))), qf[ks], sc[kvt]);
      }
      __builtin_amdgcn_s_setprio(0);
    }
    float psum = 0.f;
    #pragma unroll
    for(int kvt=0;kvt<2;kvt++){
      #pragma unroll
      for(int r4=0;r4<4;r4++){
        const float4 mk = vM[kvt*4+r4];
        const float p0 = fexp2(fmaf(sc[kvt][r4*4+0], SCALE2_, mk.x));
        const float p1 = fexp2(fmaf(sc[kvt][r4*4+1], SCALE2_, mk.y));
        const float p2 = fexp2(fmaf(sc[kvt][r4*4+2], SCALE2_, mk.z));
        const float p3 = fexp2(fmaf(sc[kvt][r4*4+3], SCALE2_, mk.w));
        sc[kvt][r4*4+0]=p0; sc[kvt][r4*4+1]=p1;
        sc[kvt][r4*4+2]=p2; sc[kvt][r4*4+3]=p3;
        psum += (p0+p1)+(p2+p3);
      }
    }
    l_run += psum;
    unsigned w_[2][4][2];
    #pragma unroll
    for(int kvt=0;kvt<2;kvt++)
      #pragma unroll
      for(int r4=0;r4<4;r4++){
        w_[kvt][r4][0] = cvtpk(sc[kvt][r4*4+0], sc[kvt][r4*4+1]);
        w_[kvt][r4][1] = cvtpk(sc[kvt][r4*4+2], sc[kvt][r4*4+3]);
      }
    { const unsigned short* Sv = &lds[cur][1][0];
      __builtin_amdgcn_s_setprio(1);
      #pragma unroll
      for(int kvs=0;kvs<4;kvs++){
        const int kvt = kvs>>1, k2 = (kvs&1)*2;
        const unsigned wa0 = w_[kvt][k2  ][0], wa1 = w_[kvt][k2  ][1];
        const unsigned wb0 = w_[kvt][k2+1][0], wb1 = w_[kvt][k2+1][1];
        const unsigned own0 = hi? wb0:wa0, own1 = hi? wb1:wa1;
        const unsigned snd0 = hi? wa0:wb0, snd1 = hi? wa1:wb1;
        const unsigned rcv0 = __shfl_xor(snd0, 32, 64);
        const unsigned rcv1 = __shfl_xor(snd1, 32, 64);
        union{ unsigned u[4]; bf16x8 v; } ap;
        ap.u[0] = hi? rcv0:own0;  ap.u[1] = hi? rcv1:own1;
        ap.u[2] = hi? own0:rcv0;  ap.u[3] = hi? own1:rcv1;
        #pragma unroll
        for(int ht=0;ht<4;ht++)
          oc[ht] = mf32(ap.v, ld_frag(Sv + rowV + ht*2048 + (cbsV ^ (kvs*16))), oc[ht]);
      }
      __builtin_amdgcn_s_setprio(0);
    }
    if(tt<NT_-1){ writeK(cur^1); writeV(cur^1); }
    __syncthreads();
  }

  const float l_tot = l_run + __shfl_xor(l_run, 32, 64);
  if(lane < 32){
    lbuf[((long)bk*NSP + sp)*M_ + wid*32 + lane] = l_tot;
  }
  unsigned short* np_ = num + (((long)bk*NSP + sp)*M_ + wid*32)*HD_;
  #pragma unroll
  for(int ht=0;ht<4;ht++)
    #pragma unroll
    for(int r4=0;r4<4;r4++)
      #pragma unroll
      for(int rr=0;rr<4;rr++){
        const int q = rr + 8*r4 + 4*hi;
        np_[(long)q*HD_ + ht*32 + l31] = f2b(oc[ht][r4*4+rr]);
      }
}

// ---------------- K4: combine split-KV partials (uniform weights, uint lds) -
// 64 threads; each folds 2 adjacent d via one uint load; one rcp per thread.
__global__ __launch_bounds__(64) void k_comb(
    const unsigned short* __restrict__ num, const float* __restrict__ lbuf,
    unsigned short* __restrict__ attnb)
{
  const int q = blockIdx.x, kvh = blockIdx.y, b = blockIdx.z, d2 = threadIdx.x;
  const int bk = b*NKV_ + kvh;
  float den = 0.f, a0 = 0.f, a1 = 0.f;
  #pragma unroll
  for(int c=0;c<NSP;c++){
    const long ix = ((long)bk*NSP + c)*M_ + q;
    den += lbuf[ix];
    const unsigned u = *(const unsigned*)(num + ix*HD_ + 2*d2);
    a0 += b2f((unsigned short)(u & 0xffffu));
    a1 += b2f((unsigned short)(u >> 16));
  }
  const float r = 1.0f / den;
  const int g = q>>5, s = q&31, h = kvh*G_ + g;
  *(unsigned*)(attnb + ((long)(b*S_+s))*2048 + h*HD_ + 2*d2) = cvtpk(a0*r, a1*r);
}

// ---------------- K5: output projection GEMM, split-K=4 ----------------
__global__ __launch_bounds__(256) void k_gemm_o(
    const unsigned short* __restrict__ A,
    const float* __restrict__ W,
    float* __restrict__ owsp)
{
  __shared__ unsigned short As[64][56];
  __shared__ unsigned short Bs[64][56];
  const int n0 = blockIdx.x*64, m0 = blockIdx.y*64, kz = blockIdx.z;
  const int t = threadIdx.x, lane = t&63, wid = t>>6;
  const int wr = wid>>1, wc = wid&1, l15 = lane&15, lq = lane>>4;
  const int ar = t>>2,  ac = (t&3)*8;
  const int bk = t>>5,  bn = (t&31)*2;
  f32x4 acc[2][2] = {};
  for(int k0 = kz*512; k0 < kz*512 + 512; k0 += 32){
    __syncthreads();
    *(uint4*)(&As[ar][ac]) = *(const uint4*)(A + (m0+ar)*2048 + k0 + ac);
    #pragma unroll
    for(int p=0;p<4;p++){
      const int kk = bk + p*8;
      const float2 wv = *(const float2*)(W + (long)(k0+kk)*2048 + n0 + bn);
      Bs[bn  ][kk] = f2b(wv.x);
      Bs[bn+1][kk] = f2b(wv.y);
    }
    __syncthreads();
    const bf16x8 a0 = ld_frag(&As[wr*32      + l15][lq*8]);
    const bf16x8 a1 = ld_frag(&As[wr*32 + 16 + l15][lq*8]);
    const bf16x8 b0 = ld_frag(&Bs[wc*32      + l15][lq*8]);
    const bf16x8 b1 = ld_frag(&Bs[wc*32 + 16 + l15][lq*8]);
    acc[0][0] = mf(a0,b0,acc[0][0]);
    acc[0][1] = mf(a0,b1,acc[0][1]);
    acc[1][0] = mf(a1,b0,acc[1][0]);
    acc[1][1] = mf(a1,b1,acc[1][1]);
  }
  float* out = owsp + (long)kz*M_*2048;
  #pragma unroll
  for(int mi=0;mi<2;mi++)
    #pragma unroll
    for(int nj=0;nj<2;nj++){
      const int col = n0 + wc*32 + nj*16 + l15;
      #pragma unroll
      for(int rr=0;rr<4;rr++){
        const int row = m0 + wr*32 + mi*16 + lq*4 + rr;
        out[row*2048 + col] = acc[mi][nj][rr];
      }
    }
}

// ---------------- K6: fold the four O K-quarters ----------------
__global__ __launch_bounds__(256) void k_ored(const float* __restrict__ a,
                                              float* __restrict__ out){
  const int i = (blockIdx.x*256 + threadIdx.x)*4;
  const long MN = (long)M_*2048;
  const float4 x = *(const float4*)(a + i);
  const float4 y = *(const float4*)(a + MN + i);
  const float4 z = *(const float4*)(a + 2*MN + i);
  const float4 w = *(const float4*)(a + 3*MN + i);
  float4 o; o.x=(x.x+y.x)+(z.x+w.x); o.y=(x.y+y.y)+(z.y+w.y);
            o.z=(x.z+y.z)+(z.z+w.z); o.w=(x.w+y.w)+(z.w+w.w);
  *(float4*)(out + i) = o;
}

extern "C" void kernel_launch(void* const* d_in, const int* in_sizes, int n_in,
                              void* d_out, int out_size, void* d_ws, size_t ws_size,
                              hipStream_t stream){
  (void)in_sizes; (void)n_in; (void)out_size; (void)ws_size;
  const float* hs   = (const float*)d_in[0];
  const float* cosb = (const float*)d_in[1];
  const float* sinb = (const float*)d_in[2];
  const float* kc   = (const float*)d_in[3];
  const float* vc   = (const float*)d_in[4];
  const float* mask = (const float*)d_in[5];
  const int*   rp   = (const int*)  d_in[6];
  const float* qw   = (const float*)d_in[7];
  const float* qb   = (const float*)d_in[8];
  const float* kw   = (const float*)d_in[9];
  const float* kb   = (const float*)d_in[10];
  const float* vw   = (const float*)d_in[11];
  const float* vb   = (const float*)d_in[12];
  const float* ow   = (const float*)d_in[13];
  char* ws = (char*)d_ws;
  // ws layout (bytes)
  float*          rawp  = (float*)         (ws + 0);          // 10,485,760 (4 K-quarters)
  unsigned short* Qb    = (unsigned short*)(ws + 10485760);   //  1,048,576
  float*          KnF   = (float*)         (ws + 11534336);   //    262,144
  float*          VnF   = (float*)         (ws + 11796480);   //    262,144
  unsigned short* attnb = (unsigned short*)(ws + 12058624);   //  1,048,576
  float*          lbuf  = (float*)         (ws + 13107200);   //    262,144
  unsigned short* num   = (unsigned short*)(ws + 13369344);   // 16,777,216
  float*          owsp  = (float*)         (ws + 30146560);   //  8,388,608 (4 quarters)
  float*          msw   = (float*)         (ws + 38535168);   //  8,388,608 (end ~46.9 MB)
  float* outp = (float*)d_out;

  k_gemm_qkv<<<dim3(40,4,4),     dim3(256),  0, stream>>>(hs, qw,kw,vw, qb,kb,vb, rawp);
  k_mswz    <<<dim3(2048),       dim3(256),  0, stream>>>(mask, msw);
  k_rope    <<<dim3(256,20),     dim3(128),  0, stream>>>(rawp, cosb, sinb, Qb, KnF, VnF);
  k_attn    <<<dim3(NSP,2,8),    dim3(512),  0, stream>>>(Qb, KnF, VnF, kc, vc, msw, rp, num, lbuf);
  k_comb    <<<dim3(256,2,8),    dim3(64),   0, stream>>>(num, lbuf, attnb);
  k_gemm_o  <<<dim3(32,4,4),     dim3(256),  0, stream>>>(attnb, ow, owsp);
  k_ored    <<<dim3(512),        dim3(256),  0, stream>>>(owsp, outp);
}